// Round 9
// baseline (243.431 us; speedup 1.0000x reference)
//
#include <hip/hip_runtime.h>
#include <hip/hip_bf16.h>
#include <math.h>

#define N_NODES 50000
#define N_EDGES 800000
#define D_FEAT  128
#define EPSF    1e-12f

#define NPG     120            // nodes per coarse group
#define NG      417            // ceil(50000/120)
#define CHUNK_E 2048           // edges per scatter chunk (r8: 4096 -> halve serial tail)
#define NCHUNK  391            // ceil(800000/2048)
#define GCAP    2560           // per-group bucket capacity (mean 1919, sd 44; cannot overflow)
#define ELCAP   768            // per-block (32-node) staged edge cap (mean 512, sd 22.6 -> +11 sd)

// ---------------- workspace layout (bytes) ----------------
#define OFF_U2      0          // 512
#define OFF_GCUR    1024       // NG*4 = 1668 (group cursors; final values = group counts)
#define OFF_ES      4096       // 200000  (es[v] = exp(h[v].u2); softmax shift-free, |dot|<~5)
#define OFF_ROWPTR  204800     // 200004
#define OFF_WTN     405504     // 32768 bf16 W_node^T
#define OFF_WTG     438272     // 32768 bf16 W_neigh^T
#define OFF_SSRCW   471040     // 800000 * 8 = 6400000 (int2 {src, bits(es[src])})
#define OFF_HB      6871040    // 12800000 bf16 h
#define OFF_BUCKET  19671040   // 417*2560*4 = 4270080 (total 23.9 MB)

typedef __attribute__((ext_vector_type(8))) short bf8;
typedef __attribute__((ext_vector_type(4))) float f4;

// u2[k] = sum_j W_coef[k][j] * W_red[128+j]; also zeroes the group cursors.
__global__ void make_u2_kernel(const float* __restrict__ W_coef,
                               const float* __restrict__ W_red,
                               float* __restrict__ u2, int* __restrict__ gcursor) {
    __shared__ float wr[128];
    int k = threadIdx.x;  // 128 threads
    wr[k] = W_red[128 + k];
    for (int i = k; i < NG; i += 128) gcursor[i] = 0;
    __syncthreads();
    const float4* row = (const float4*)(W_coef + k * 128);
    float acc = 0.f;
    #pragma unroll
    for (int j = 0; j < 32; ++j) {
        float4 v = row[j];
        acc += v.x * wr[4*j] + v.y * wr[4*j+1] + v.z * wr[4*j+2] + v.w * wr[4*j+3];
    }
    u2[k] = acc;
}

// Fused, three block roles (independent work overlapped in one dispatch):
//   [0,12500):      wave-per-node -> es[v]=exp(dot(h[v],u2)) + hb[v]=bf16(h[v])
//   [12500,12564):  transpose W_node/W_neigh to bf16 output-major
//   [12564,12955):  2-pass bucket scatter: LDS count per group -> ONE global
//                   atomicAdd per (chunk,group) reserves bucket space ->
//                   re-read edges, LDS rank, write packed (src | dst_local<<16).
__global__ __launch_bounds__(256) void prep_kernel(
        const float* __restrict__ h, const float* __restrict__ u2,
        const float* __restrict__ Wn, const float* __restrict__ Wg,
        const int* __restrict__ src, const int* __restrict__ dst,
        float* __restrict__ es, unsigned short* __restrict__ hb,
        unsigned short* __restrict__ WtN, unsigned short* __restrict__ WtG,
        int* __restrict__ gcursor, int* __restrict__ bucket) {
    int b = blockIdx.x;
    if (b < 12500) {
        int node = b * 4 + (threadIdx.x >> 6);   // 50000 = 12500*4 exactly
        int lane = threadIdx.x & 63;
        float2 hv = ((const float2*)(h + (size_t)node * 128))[lane];
        float2 uv = ((const float2*)u2)[lane];
        float v = hv.x * uv.x + hv.y * uv.y;
        #pragma unroll
        for (int off = 32; off; off >>= 1) v += __shfl_xor(v, off);
        if (lane == 0) es[node] = __expf(v);  // no segment-max: shift-invariant, |v|<~5
        __hip_bfloat162 p = __float22bfloat162_rn(hv);
        ((unsigned int*)(hb + (size_t)node * 128))[lane] = *(unsigned int*)&p;
    } else if (b < 12564) {
        int idx = (b - 12500) * 256 + threadIdx.x;   // 0..16383
        int n = idx >> 7, k = idx & 127;
        __hip_bfloat16 a = __float2bfloat16(Wn[k * 128 + n]);
        __hip_bfloat16 g = __float2bfloat16(Wg[k * 128 + n]);
        WtN[n * 128 + k] = *(unsigned short*)&a;
        WtG[n * 128 + k] = *(unsigned short*)&g;
    } else {
        __shared__ int lh[NG];
        __shared__ int base[NG];
        __shared__ int cnt2[NG];
        int chunk = b - 12564;
        int tid = threadIdx.x;
        for (int i = tid; i < NG; i += 256) { lh[i] = 0; cnt2[i] = 0; }
        __syncthreads();
        int base_e = chunk * CHUNK_E;
        #pragma unroll
        for (int it = 0; it < CHUNK_E / 256; ++it) {
            int e = base_e + it * 256 + tid;
            if (e < N_EDGES) atomicAdd(&lh[(unsigned)dst[e] / NPG], 1);
        }
        __syncthreads();
        for (int i = tid; i < NG; i += 256) {
            int c = lh[i];
            base[i] = c ? atomicAdd(&gcursor[i], c) : 0;
        }
        __syncthreads();
        #pragma unroll
        for (int it = 0; it < CHUNK_E / 256; ++it) {
            int e = base_e + it * 256 + tid;
            if (e < N_EDGES) {
                int d = dst[e];
                int g = (unsigned)d / NPG;
                int r = atomicAdd(&cnt2[g], 1);
                int p = base[g] + r;
                if (p < GCAP)
                    bucket[(size_t)g * GCAP + p] = src[e] | ((d - g * NPG) << 16);
            }
        }
    }
}

// Fine pass: one block per group. Computes its own base offset (sum of prior
// group counts, L2-hot), then builds exact per-node row_ptr and node-sorted
// (src, w=es[src]) pairs. All atomics in LDS (int -- native ds_add).
__global__ __launch_bounds__(128) void fine_kernel(
        const int* __restrict__ gcnt, const int* __restrict__ bucket,
        const float* __restrict__ es,
        int* __restrict__ row_ptr, int2* __restrict__ ssrc_w) {
    __shared__ int cnt[NPG];
    __shared__ int cnt2[NPG];
    __shared__ int sexcl[NPG];
    __shared__ int ws[2];
    __shared__ int red[2];
    int g = blockIdx.x, tid = threadIdx.x;
    int lane = tid & 63, wid = tid >> 6;

    // beg = sum_{g'<g} gcnt[g']
    int partial = 0;
    for (int i = tid; i < g; i += 128) partial += gcnt[i];
    #pragma unroll
    for (int off = 32; off; off >>= 1) partial += __shfl_down(partial, off);
    if (lane == 0) red[wid] = partial;
    if (tid < NPG) { cnt[tid] = 0; cnt2[tid] = 0; }
    __syncthreads();
    int beg = red[0] + red[1];
    int cnt_g = min(gcnt[g], GCAP);
    const int* bk = bucket + (size_t)g * GCAP;

    for (int i = tid; i < cnt_g; i += 128)
        atomicAdd(&cnt[bk[i] >> 16], 1);
    __syncthreads();
    // exclusive scan of 120 counts with 128 threads (2 waves)
    int v = (tid < NPG) ? cnt[tid] : 0;
    int incl = v;
    #pragma unroll
    for (int off = 1; off < 64; off <<= 1) {
        int t = __shfl_up(incl, off);
        if (lane >= off) incl += t;
    }
    if (lane == 63) ws[wid] = incl;
    __syncthreads();
    if (wid == 1) incl += ws[0];
    int excl = incl - v;
    if (tid < NPG) sexcl[tid] = excl;
    int node = g * NPG + tid;
    if (tid < NPG && node < N_NODES) row_ptr[node] = beg + excl;
    if (g == NG - 1 && tid == 0) row_ptr[N_NODES] = N_EDGES;
    __syncthreads();
    for (int i = tid; i < cnt_g; i += 128) {
        int p = bk[i];
        int loc = p >> 16;
        int sv = p & 0xFFFF;
        float wv = es[sv];
        int r = atomicAdd(&cnt2[loc], 1);
        ssrc_w[beg + sexcl[loc] + r] = make_int2(sv, __float_as_int(wv));
    }
}

// Fused aggregate + GEMM + normalize. Block = 512 threads = 8 waves = 32
// nodes; 16-lane group per node (r7 structure, kept).
// r8 post-mortem: agg's 62.5us was L2-CAPACITY-bound, not latency: the
// 256B-row gather touches hb (12.8 MB) randomly, but per-XCD L2 is 4 MB ->
// ~2/3 of the 205 MB logical gather spilled to L3/HBM (FETCH 87 MB).
// Fix: K-SLICED GATHER. 4 passes over the edge list, pass ks gathers only
// bytes [ks*64, ks*64+64) of each row = EXACTLY one 64B line per edge;
// slice working set = 50000 lines x 64B = 3.2 MB < 4 MB L2 -> after
// warm-up every gather is an L2 hit. Per-element FMA order over edges is
// unchanged -> bit-identical result. Edge pairs are staged once into LDS
// (block's 32 nodes are CONTIGUOUS in ssrc_w -> one coalesced stage) so
// the 4 passes don't re-read L2.
// Phase 2: unchanged r7 MFMA scheme (2 row-tiles x {2 halves x 2 t-quads}).
__global__ __launch_bounds__(512) void agg_gemm_kernel(
        const int* __restrict__ row_ptr, const int2* __restrict__ ssrc_w,
        const unsigned short* __restrict__ hb,
        const unsigned short* __restrict__ WtN, const unsigned short* __restrict__ WtG,
        const float* __restrict__ b_node, const float* __restrict__ b_neigh,
        float* __restrict__ out) {
    __shared__ __align__(8) int2 el[ELCAP];
    __shared__ __align__(16) unsigned short aggt[32][136];  // +8 pad
    __shared__ float ssrp[8][16];                           // [wave][rowInTile]
    int tid = threadIdx.x;
    int wave = tid >> 6, lane = tid & 63;
    int node0 = blockIdx.x * 32;
    int q = lane >> 4, l16 = lane & 15;

    // ---- stage the block's contiguous edge-pair range into LDS ----
    int ebeg = row_ptr[min(node0, N_NODES)];
    int eend = row_ptr[min(node0 + 32, N_NODES)];
    int ecnt = eend - ebeg;
    for (int i = tid; i < min(ecnt, ELCAP); i += 512) el[i] = ssrc_w[ebeg + i];
    __syncthreads();

    // ---- phase 1: group g32 = tid>>4 aggregates node node0+g32, k-sliced ----
    {
        int g32 = tid >> 4;
        int node = node0 + g32;
        int beg = 0, deg = 0;
        if (node < N_NODES) {
            beg = row_ptr[node];
            deg = row_ptr[node + 1] - beg;
        }
        int rbeg = beg - ebeg;
        float inv;
        {   // ks = 0 pass also computes wsum
            float a0 = 0.f, a1 = 0.f, wsum = 0.f;
            #pragma unroll 4
            for (int i = 0; i < deg; ++i) {
                int ri = rbeg + i;
                int2 pw = (ri < ELCAP) ? el[ri] : ssrc_w[beg + i];
                float wv = __int_as_float(pw.y);
                wsum += wv;                    // uniform across the group
                unsigned hv = *(const unsigned*)(hb + (size_t)pw.x * 128 + l16 * 2);
                a0 = fmaf(wv, __uint_as_float(hv << 16),         a0);
                a1 = fmaf(wv, __uint_as_float(hv & 0xFFFF0000u), a1);
            }
            inv = 1.f / (wsum + EPSF);
            __hip_bfloat162 p = __float22bfloat162_rn(make_float2(a0 * inv, a1 * inv));
            *(unsigned*)&aggt[g32][l16 * 2] = *(unsigned*)&p;
        }
        #pragma unroll
        for (int ks = 1; ks < 4; ++ks) {
            float a0 = 0.f, a1 = 0.f;
            #pragma unroll 4
            for (int i = 0; i < deg; ++i) {
                int ri = rbeg + i;
                int2 pw = (ri < ELCAP) ? el[ri] : ssrc_w[beg + i];
                float wv = __int_as_float(pw.y);
                unsigned hv = *(const unsigned*)(hb + (size_t)pw.x * 128 + ks * 32 + l16 * 2);
                a0 = fmaf(wv, __uint_as_float(hv << 16),         a0);
                a1 = fmaf(wv, __uint_as_float(hv & 0xFFFF0000u), a1);
            }
            __hip_bfloat162 p = __float22bfloat162_rn(make_float2(a0 * inv, a1 * inv));
            *(unsigned*)&aggt[g32][ks * 32 + l16 * 2] = *(unsigned*)&p;
        }
    }
    __syncthreads();

    // ---- phase 2: rt = wave&1 (row-tile), tq = wave>>1 (col-quad) ----
    int rt = wave & 1, tq = wave >> 1;
    int half = tq >> 1, tb = (tq & 1) * 4;
    const unsigned short* Wt = half ? WtG : WtN;
    size_t arow = (size_t)min(node0 + rt * 16 + l16, N_NODES - 1);

    f4 acc[4];
    #pragma unroll
    for (int tt = 0; tt < 4; ++tt) acc[tt] = (f4){0.f, 0.f, 0.f, 0.f};
    #pragma unroll
    for (int kc = 0; kc < 4; ++kc) {
        int kbase = kc * 32 + q * 8;
        bf8 a = half ? *(const bf8*)&aggt[rt * 16 + l16][kbase]
                     : *(const bf8*)(hb + arow * 128 + kbase);
        #pragma unroll
        for (int tt = 0; tt < 4; ++tt) {
            int t = tb + tt;
            bf8 bb = *(const bf8*)(Wt + (size_t)(t * 16 + l16) * 128 + kbase);
            acc[tt] = __builtin_amdgcn_mfma_f32_16x16x32_bf16(a, bb, acc[tt], 0, 0, 0);
        }
    }

    float ssr[4] = {0.f, 0.f, 0.f, 0.f};
    #pragma unroll
    for (int tt = 0; tt < 4; ++tt) {
        int t = tb + tt;
        float bv = (half ? b_neigh : b_node)[t * 16 + l16];
        #pragma unroll
        for (int r = 0; r < 4; ++r) {
            acc[tt][r] += bv;
            ssr[r] = fmaf(acc[tt][r], acc[tt][r], ssr[r]);
        }
    }
    #pragma unroll
    for (int r = 0; r < 4; ++r) {
        ssr[r] += __shfl_xor(ssr[r], 1);
        ssr[r] += __shfl_xor(ssr[r], 2);
        ssr[r] += __shfl_xor(ssr[r], 4);
        ssr[r] += __shfl_xor(ssr[r], 8);
    }
    if (l16 == 0) {
        #pragma unroll
        for (int r = 0; r < 4; ++r) ssrp[wave][q * 4 + r] = ssr[r];
    }
    __syncthreads();
    #pragma unroll
    for (int r = 0; r < 4; ++r) {
        int row = q * 4 + r;                   // C/D: row = quad*4 + reg
        float tot = ssrp[rt][row] + ssrp[rt + 2][row] +
                    ssrp[rt + 4][row] + ssrp[rt + 6][row];
        float sc = rsqrtf(fmaxf(tot, EPSF));
        int node = node0 + rt * 16 + row;
        if (node < N_NODES) {
            float* o = out + (size_t)node * 256 + half * 128;
            #pragma unroll
            for (int tt = 0; tt < 4; ++tt)
                o[(tb + tt) * 16 + l16] = acc[tt][r] * sc;
        }
    }
}

extern "C" void kernel_launch(void* const* d_in, const int* in_sizes, int n_in,
                              void* d_out, int out_size, void* d_ws, size_t ws_size,
                              hipStream_t stream) {
    const float* h       = (const float*)d_in[0];
    const int*   src     = (const int*)d_in[1];
    const int*   dst     = (const int*)d_in[2];
    const float* W_coef  = (const float*)d_in[3];
    // b_coef (d_in[4]) and b_red (d_in[6]) cancel under per-segment softmax shift-invariance
    const float* W_red   = (const float*)d_in[5];
    const float* W_node  = (const float*)d_in[7];
    const float* b_node  = (const float*)d_in[8];
    const float* W_neigh = (const float*)d_in[9];
    const float* b_neigh = (const float*)d_in[10];
    float* out = (float*)d_out;

    char* w = (char*)d_ws;
    float*          u2      = (float*)(w + OFF_U2);
    int*            gcursor = (int*)(w + OFF_GCUR);
    float*          es      = (float*)(w + OFF_ES);
    int*            row_ptr = (int*)(w + OFF_ROWPTR);
    unsigned short* WtN     = (unsigned short*)(w + OFF_WTN);
    unsigned short* WtG     = (unsigned short*)(w + OFF_WTG);
    int2*           ssrc_w  = (int2*)(w + OFF_SSRCW);
    unsigned short* hb      = (unsigned short*)(w + OFF_HB);
    int*            bucket  = (int*)(w + OFF_BUCKET);

    make_u2_kernel<<<1, 128, 0, stream>>>(W_coef, W_red, u2, gcursor);
    prep_kernel<<<12500 + 64 + NCHUNK, 256, 0, stream>>>(
        h, u2, W_node, W_neigh, src, dst, es, hb, WtN, WtG, gcursor, bucket);
    fine_kernel<<<NG, 128, 0, stream>>>(gcursor, bucket, es, row_ptr, ssrc_w);
    agg_gemm_kernel<<<(N_NODES + 31) / 32, 512, 0, stream>>>(
        row_ptr, ssrc_w, hb, WtN, WtG, b_node, b_neigh, out);
}

// Round 10
// 195.938 us; speedup vs baseline: 1.2424x; 1.2424x over previous
//
#include <hip/hip_runtime.h>
#include <hip/hip_bf16.h>
#include <math.h>

#define N_NODES 50000
#define N_EDGES 800000
#define D_FEAT  128
#define EPSF    1e-12f

#define NPG     120            // nodes per coarse group
#define NG      417            // ceil(50000/120)
#define CHUNK_E 4096           // edges per scatter chunk
#define NCHUNK  196            // ceil(800000/4096)
#define GCAP    2560           // per-group bucket capacity (mean 1919, sd 44; cannot overflow)
#define NRNG    8              // src ranges (src>>13 -> 0..6; 8 slots)

// ---------------- workspace layout (bytes) ----------------
#define OFF_U2      0          // 512
#define OFF_GCUR    1024       // NG*4 = 1668 (group cursors; final values = group counts)
#define OFF_ES      4096       // 200000  (es[v] = exp(h[v].u2); softmax shift-free, |dot|<~5)
#define OFF_ROWPTR  204800     // 200004
#define OFF_WTN     405504     // 32768 bf16 W_node^T
#define OFF_WTG     438272     // 32768 bf16 W_neigh^T
#define OFF_SSRCW   471040     // 800000 * 8 = 6400000 (int2 {src, bits(es[src])})
#define OFF_HB      6871040    // 12800000 bf16 h
#define OFF_BUCKET  19671040   // 417*2560*4 = 4270080 (total 23.9 MB)

typedef __attribute__((ext_vector_type(8))) short bf8;
typedef __attribute__((ext_vector_type(4))) float f4;

// u2[k] = sum_j W_coef[k][j] * W_red[128+j]; also zeroes the group cursors.
__global__ void make_u2_kernel(const float* __restrict__ W_coef,
                               const float* __restrict__ W_red,
                               float* __restrict__ u2, int* __restrict__ gcursor) {
    __shared__ float wr[128];
    int k = threadIdx.x;  // 128 threads
    wr[k] = W_red[128 + k];
    for (int i = k; i < NG; i += 128) gcursor[i] = 0;
    __syncthreads();
    const float4* row = (const float4*)(W_coef + k * 128);
    float acc = 0.f;
    #pragma unroll
    for (int j = 0; j < 32; ++j) {
        float4 v = row[j];
        acc += v.x * wr[4*j] + v.y * wr[4*j+1] + v.z * wr[4*j+2] + v.w * wr[4*j+3];
    }
    u2[k] = acc;
}

// Fused, three block roles. ROLE ORDER CHANGED (r9 post-mortem): the 196
// scatter-role blocks used to sit at the END of the grid -> they started
// after the 12500 conversion blocks and ran as a ~1-block/CU serial tail.
// Putting them FIRST overlaps the scatter under the conversion stream.
//   [0,196):        2-pass bucket scatter: LDS count per group -> ONE global
//                   atomicAdd per (chunk,group) reserves bucket space ->
//                   re-read edges, LDS rank, write packed (src | dst_local<<16).
//   [196,260):      transpose W_node/W_neigh to bf16 output-major
//   [260,12760):    wave-per-node -> es[v]=exp(dot(h[v],u2)) + hb[v]=bf16(h[v])
__global__ __launch_bounds__(256) void prep_kernel(
        const float* __restrict__ h, const float* __restrict__ u2,
        const float* __restrict__ Wn, const float* __restrict__ Wg,
        const int* __restrict__ src, const int* __restrict__ dst,
        float* __restrict__ es, unsigned short* __restrict__ hb,
        unsigned short* __restrict__ WtN, unsigned short* __restrict__ WtG,
        int* __restrict__ gcursor, int* __restrict__ bucket) {
    int b = blockIdx.x;
    if (b < NCHUNK) {
        __shared__ int lh[NG];
        __shared__ int base[NG];
        __shared__ int cnt2[NG];
        int chunk = b;
        int tid = threadIdx.x;
        for (int i = tid; i < NG; i += 256) { lh[i] = 0; cnt2[i] = 0; }
        __syncthreads();
        int base_e = chunk * CHUNK_E;
        #pragma unroll
        for (int it = 0; it < CHUNK_E / 256; ++it) {
            int e = base_e + it * 256 + tid;
            if (e < N_EDGES) atomicAdd(&lh[(unsigned)dst[e] / NPG], 1);
        }
        __syncthreads();
        for (int i = tid; i < NG; i += 256) {
            int c = lh[i];
            base[i] = c ? atomicAdd(&gcursor[i], c) : 0;
        }
        __syncthreads();
        #pragma unroll
        for (int it = 0; it < CHUNK_E / 256; ++it) {
            int e = base_e + it * 256 + tid;
            if (e < N_EDGES) {
                int d = dst[e];
                int g = (unsigned)d / NPG;
                int r = atomicAdd(&cnt2[g], 1);
                int p = base[g] + r;
                if (p < GCAP)
                    bucket[(size_t)g * GCAP + p] = src[e] | ((d - g * NPG) << 16);
            }
        }
    } else if (b < NCHUNK + 64) {
        int idx = (b - NCHUNK) * 256 + threadIdx.x;   // 0..16383
        int n = idx >> 7, k = idx & 127;
        __hip_bfloat16 a = __float2bfloat16(Wn[k * 128 + n]);
        __hip_bfloat16 g = __float2bfloat16(Wg[k * 128 + n]);
        WtN[n * 128 + k] = *(unsigned short*)&a;
        WtG[n * 128 + k] = *(unsigned short*)&g;
    } else {
        int node = (b - NCHUNK - 64) * 4 + (threadIdx.x >> 6);  // 50000 = 12500*4
        int lane = threadIdx.x & 63;
        float2 hv = ((const float2*)(h + (size_t)node * 128))[lane];
        float2 uv = ((const float2*)u2)[lane];
        float v = hv.x * uv.x + hv.y * uv.y;
        #pragma unroll
        for (int off = 32; off; off >>= 1) v += __shfl_xor(v, off);
        if (lane == 0) es[node] = __expf(v);  // no segment-max: shift-invariant, |v|<~5
        __hip_bfloat162 p = __float22bfloat162_rn(hv);
        ((unsigned int*)(hb + (size_t)node * 128))[lane] = *(unsigned int*)&p;
    }
}

// Fine pass: one block per group. Builds per-node row_ptr and node-sorted
// (src, w=es[src]) pairs, with edges WITHIN each node ordered by src-range
// (bin key = loc*NRNG + (src>>13), 960 bins). All agg blocks then walk
// src-ranges 0..7 in roughly the same order -> the gather's hot set at any
// instant is ~2-3 ranges (~4 MB) instead of all of hb (12.8 MB) -> per-XCD
// L2-resident. Within-node order was already nondeterministic, so this
// reordering changes nothing semantically.
__global__ __launch_bounds__(128) void fine_kernel(
        const int* __restrict__ gcnt, const int* __restrict__ bucket,
        const float* __restrict__ es,
        int* __restrict__ row_ptr, int2* __restrict__ ssrc_w) {
    __shared__ int cnt[NPG * NRNG];
    __shared__ int cur[NPG * NRNG];
    __shared__ int ws[2];
    __shared__ int red[2];
    int g = blockIdx.x, tid = threadIdx.x;
    int lane = tid & 63, wid = tid >> 6;

    // beg = sum_{g'<g} gcnt[g']
    int partial = 0;
    for (int i = tid; i < g; i += 128) partial += gcnt[i];
    #pragma unroll
    for (int off = 32; off; off >>= 1) partial += __shfl_down(partial, off);
    if (lane == 0) red[wid] = partial;
    for (int i = tid; i < NPG * NRNG; i += 128) cnt[i] = 0;
    __syncthreads();
    int beg = red[0] + red[1];
    int cnt_g = min(gcnt[g], GCAP);
    const int* bk = bucket + (size_t)g * GCAP;

    // count (loc, srcRange) bins
    for (int i = tid; i < cnt_g; i += 128) {
        int p = bk[i];
        atomicAdd(&cnt[(p >> 16) * NRNG + ((p & 0xFFFF) >> 13)], 1);
    }
    __syncthreads();
    // per-node total + in-node bin bases (serial over 8 bins, thread = node)
    int v = 0;
    if (tid < NPG) {
        int bsum = 0;
        #pragma unroll
        for (int r = 0; r < NRNG; ++r) {
            cur[tid * NRNG + r] = bsum;
            bsum += cnt[tid * NRNG + r];
        }
        v = bsum;
    }
    // exclusive scan of 120 node totals (2 waves)
    int incl = v;
    #pragma unroll
    for (int off = 1; off < 64; off <<= 1) {
        int t = __shfl_up(incl, off);
        if (lane >= off) incl += t;
    }
    if (lane == 63) ws[wid] = incl;
    __syncthreads();
    if (wid == 1) incl += ws[0];
    int excl = incl - v;
    int node = g * NPG + tid;
    if (tid < NPG && node < N_NODES) row_ptr[node] = beg + excl;
    if (g == NG - 1 && tid == 0) row_ptr[N_NODES] = N_EDGES;
    __syncthreads();
    if (tid < NPG) {
        #pragma unroll
        for (int r = 0; r < NRNG; ++r) cur[tid * NRNG + r] += excl;
    }
    __syncthreads();
    // scatter in (node, srcRange) order
    for (int i = tid; i < cnt_g; i += 128) {
        int p = bk[i];
        int loc = p >> 16, sv = p & 0xFFFF;
        int r = atomicAdd(&cur[loc * NRNG + (sv >> 13)], 1);
        ssrc_w[beg + r] = make_int2(sv, __float_as_int(es[sv]));
    }
}

// Fused aggregate + GEMM + normalize. EXACT r7 structure (known 62.5us):
// block = 512 thr = 8 waves = 32 nodes; 16-lane group per node; per edge:
// broadcast 8B (src,w) pair + full 256B row as uint4 (16B/lane), 8 FMAs;
// wsum lane-uniform. The only change vs r7 is UPSTREAM: fine now emits
// src-range-ordered edges, so this gather walks hb range-by-range and the
// hot range stays L2-resident.
__global__ __launch_bounds__(512) void agg_gemm_kernel(
        const int* __restrict__ row_ptr, const int2* __restrict__ ssrc_w,
        const unsigned short* __restrict__ hb,
        const unsigned short* __restrict__ WtN, const unsigned short* __restrict__ WtG,
        const float* __restrict__ b_node, const float* __restrict__ b_neigh,
        float* __restrict__ out) {
    __shared__ __align__(16) unsigned short aggt[32][136];  // +8 pad
    __shared__ float ssrp[8][16];                           // [wave][rowInTile]
    int tid = threadIdx.x;
    int wave = tid >> 6, lane = tid & 63;
    int node0 = blockIdx.x * 32;
    int q = lane >> 4, l16 = lane & 15;

    // ---- phase 1: group g32 = tid>>4 aggregates node node0+g32 ----
    {
        int g32 = tid >> 4;
        int node = node0 + g32;
        int beg = 0, deg = 0;
        if (node < N_NODES) {
            beg = row_ptr[node];
            deg = row_ptr[node + 1] - beg;
        }
        float acc[8] = {0.f, 0.f, 0.f, 0.f, 0.f, 0.f, 0.f, 0.f};
        float wsum = 0.f;
        #pragma unroll 4
        for (int i = 0; i < deg; ++i) {
            int2 pw = ssrc_w[beg + i];        // 16-lane broadcast load (8B)
            float wv = __int_as_float(pw.y);
            wsum += wv;                        // uniform across the group
            uint4 hv = *(const uint4*)(hb + (size_t)pw.x * 128 + l16 * 8);
            acc[0] = fmaf(wv, __uint_as_float(hv.x << 16),        acc[0]);
            acc[1] = fmaf(wv, __uint_as_float(hv.x & 0xFFFF0000u), acc[1]);
            acc[2] = fmaf(wv, __uint_as_float(hv.y << 16),        acc[2]);
            acc[3] = fmaf(wv, __uint_as_float(hv.y & 0xFFFF0000u), acc[3]);
            acc[4] = fmaf(wv, __uint_as_float(hv.z << 16),        acc[4]);
            acc[5] = fmaf(wv, __uint_as_float(hv.z & 0xFFFF0000u), acc[5]);
            acc[6] = fmaf(wv, __uint_as_float(hv.w << 16),        acc[6]);
            acc[7] = fmaf(wv, __uint_as_float(hv.w & 0xFFFF0000u), acc[7]);
        }
        float inv = 1.f / (wsum + EPSF);
        unsigned o[4];
        #pragma unroll
        for (int j = 0; j < 4; ++j) {
            __hip_bfloat162 p = __float22bfloat162_rn(
                make_float2(acc[2*j] * inv, acc[2*j+1] * inv));
            o[j] = *(unsigned*)&p;
        }
        *(uint4*)&aggt[g32][l16 * 8] = make_uint4(o[0], o[1], o[2], o[3]);
    }
    __syncthreads();

    // ---- phase 2: rt = wave&1 (row-tile), tq = wave>>1 (col-quad) ----
    int rt = wave & 1, tq = wave >> 1;
    int half = tq >> 1, tb = (tq & 1) * 4;
    const unsigned short* Wt = half ? WtG : WtN;
    size_t arow = (size_t)min(node0 + rt * 16 + l16, N_NODES - 1);

    f4 acc[4];
    #pragma unroll
    for (int tt = 0; tt < 4; ++tt) acc[tt] = (f4){0.f, 0.f, 0.f, 0.f};
    #pragma unroll
    for (int kc = 0; kc < 4; ++kc) {
        int kbase = kc * 32 + q * 8;
        bf8 a = half ? *(const bf8*)&aggt[rt * 16 + l16][kbase]
                     : *(const bf8*)(hb + arow * 128 + kbase);
        #pragma unroll
        for (int tt = 0; tt < 4; ++tt) {
            int t = tb + tt;
            bf8 bb = *(const bf8*)(Wt + (size_t)(t * 16 + l16) * 128 + kbase);
            acc[tt] = __builtin_amdgcn_mfma_f32_16x16x32_bf16(a, bb, acc[tt], 0, 0, 0);
        }
    }

    float ssr[4] = {0.f, 0.f, 0.f, 0.f};
    #pragma unroll
    for (int tt = 0; tt < 4; ++tt) {
        int t = tb + tt;
        float bv = (half ? b_neigh : b_node)[t * 16 + l16];
        #pragma unroll
        for (int r = 0; r < 4; ++r) {
            acc[tt][r] += bv;
            ssr[r] = fmaf(acc[tt][r], acc[tt][r], ssr[r]);
        }
    }
    #pragma unroll
    for (int r = 0; r < 4; ++r) {
        ssr[r] += __shfl_xor(ssr[r], 1);
        ssr[r] += __shfl_xor(ssr[r], 2);
        ssr[r] += __shfl_xor(ssr[r], 4);
        ssr[r] += __shfl_xor(ssr[r], 8);
    }
    if (l16 == 0) {
        #pragma unroll
        for (int r = 0; r < 4; ++r) ssrp[wave][q * 4 + r] = ssr[r];
    }
    __syncthreads();
    #pragma unroll
    for (int r = 0; r < 4; ++r) {
        int row = q * 4 + r;                   // C/D: row = quad*4 + reg
        float tot = ssrp[rt][row] + ssrp[rt + 2][row] +
                    ssrp[rt + 4][row] + ssrp[rt + 6][row];
        float sc = rsqrtf(fmaxf(tot, EPSF));
        int node = node0 + rt * 16 + row;
        if (node < N_NODES) {
            float* o = out + (size_t)node * 256 + half * 128;
            #pragma unroll
            for (int tt = 0; tt < 4; ++tt)
                o[(tb + tt) * 16 + l16] = acc[tt][r] * sc;
        }
    }
}

extern "C" void kernel_launch(void* const* d_in, const int* in_sizes, int n_in,
                              void* d_out, int out_size, void* d_ws, size_t ws_size,
                              hipStream_t stream) {
    const float* h       = (const float*)d_in[0];
    const int*   src     = (const int*)d_in[1];
    const int*   dst     = (const int*)d_in[2];
    const float* W_coef  = (const float*)d_in[3];
    // b_coef (d_in[4]) and b_red (d_in[6]) cancel under per-segment softmax shift-invariance
    const float* W_red   = (const float*)d_in[5];
    const float* W_node  = (const float*)d_in[7];
    const float* b_node  = (const float*)d_in[8];
    const float* W_neigh = (const float*)d_in[9];
    const float* b_neigh = (const float*)d_in[10];
    float* out = (float*)d_out;

    char* w = (char*)d_ws;
    float*          u2      = (float*)(w + OFF_U2);
    int*            gcursor = (int*)(w + OFF_GCUR);
    float*          es      = (float*)(w + OFF_ES);
    int*            row_ptr = (int*)(w + OFF_ROWPTR);
    unsigned short* WtN     = (unsigned short*)(w + OFF_WTN);
    unsigned short* WtG     = (unsigned short*)(w + OFF_WTG);
    int2*           ssrc_w  = (int2*)(w + OFF_SSRCW);
    unsigned short* hb      = (unsigned short*)(w + OFF_HB);
    int*            bucket  = (int*)(w + OFF_BUCKET);

    make_u2_kernel<<<1, 128, 0, stream>>>(W_coef, W_red, u2, gcursor);
    prep_kernel<<<NCHUNK + 64 + 12500, 256, 0, stream>>>(
        h, u2, W_node, W_neigh, src, dst, es, hb, WtN, WtG, gcursor, bucket);
    fine_kernel<<<NG, 128, 0, stream>>>(gcursor, bucket, es, row_ptr, ssrc_w);
    agg_gemm_kernel<<<(N_NODES + 31) / 32, 512, 0, stream>>>(
        row_ptr, ssrc_w, hb, WtN, WtG, b_node, b_neigh, out);
}